// Round 11
// baseline (329.667 us; speedup 1.0000x reference)
//
#include <hip/hip_runtime.h>
#include <math.h>
#include <float.h>

// Problem constants (match reference)
#define B_ 2048
#define D_ 512
#define T_ 16
#define H_ 1024
#define K_ 50
#define M_ 16
#define NSWEEP 1      // validated round 9/10: absmax 6.1e-5..1.8e-4 vs 2.65e-4 threshold
#define SX_STRIDE 2656  // floats per batch in Sx ([51 rows][52 cols] + pad, 16B aligned)
#define SLAB 128        // sbuild K-slab width (shorts)
#define SROW 136        // sbuild LDS row stride in shorts

typedef __attribute__((ext_vector_type(8))) short s16x8;   // 8 bf16 (4 VGPRs)
typedef __attribute__((ext_vector_type(4))) float f32x4;   // MFMA accumulator

__device__ __forceinline__ float bsum64(float v) {
  #pragma unroll
  for (int o = 1; o < 64; o <<= 1) v += __shfl_xor(v, o);
  return v;
}
// interleaved dual butterfly-sum (two independent problems per wave)
__device__ __forceinline__ void bsum64x2(float& a, float& b) {
  #pragma unroll
  for (int o = 1; o < 64; o <<= 1) {
    float va = __shfl_xor(a, o);
    float vb = __shfl_xor(b, o);
    a += va; b += vb;
  }
}

// ---- bf16 split helpers (RNE) ----
__device__ __forceinline__ unsigned bf16_rne(float v) {
  union { float f; unsigned u; } a; a.f = v;
  return (a.u + 0x7FFFu + ((a.u >> 16) & 1u)) >> 16;
}
__device__ __forceinline__ float bf16_val(unsigned h) {
  union { unsigned u; float f; } a; a.u = h << 16;
  return a.f;
}
__device__ __forceinline__ void split_bf16(float v, unsigned short* h, unsigned short* l) {
  unsigned hh = bf16_rne(v);
  *h = (unsigned short)hh;
  *l = (unsigned short)bf16_rne(v - bf16_val(hh));
}

// ---- conversion kernels ----
// xt[b, 0:512]=x, [512:528]=t, [528:544]=0   (K padded to 544 = 17*32)
__global__ __launch_bounds__(256)
void conv_xt(const float* __restrict__ x, const float* __restrict__ t,
             unsigned short* __restrict__ xh, unsigned short* __restrict__ xl) {
  const int b = blockIdx.y;
  const int c = blockIdx.x * 256 + threadIdx.x;
  if (c >= 544) return;
  float v = 0.f;
  if (c < 512) v = x[(size_t)b * 512 + c];
  else if (c < 528) v = t[(size_t)b * 16 + (c - 512)];
  unsigned short hh, ll; split_bf16(v, &hh, &ll);
  xh[(size_t)b * 544 + c] = hh;
  xl[(size_t)b * 544 + c] = ll;
}

// straight element-wise split (W1 and P)
__global__ __launch_bounds__(256)
void conv_mat(const float* __restrict__ A, unsigned short* __restrict__ h,
              unsigned short* __restrict__ l, int n) {
  int i = blockIdx.x * 256 + threadIdx.x;
  if (i >= n) return;
  unsigned short hh, ll; split_bf16(A[i], &hh, &ll);
  h[i] = hh; l[i] = ll;
}

// w1t[h, k] = W1[k, h], k padded 528->544 with zeros.  32x32 LDS tile transpose.
__global__ __launch_bounds__(256)
void conv_w1t(const float* __restrict__ W1, unsigned short* __restrict__ th,
              unsigned short* __restrict__ tl) {
  __shared__ float tile[32][33];
  const int tx = threadIdx.x & 31, ty = threadIdx.x >> 5;   // 32 x 8
  const int kb = blockIdx.x * 32, hb = blockIdx.y * 32;
  #pragma unroll
  for (int j = 0; j < 4; j++) {
    int k = kb + ty + j * 8;
    tile[ty + j * 8][tx] = (k < 528) ? W1[(size_t)k * 1024 + hb + tx] : 0.f;
  }
  __syncthreads();
  #pragma unroll
  for (int j = 0; j < 4; j++) {
    int hrow = hb + ty + j * 8;
    float v = tile[tx][ty + j * 8];
    unsigned short hh, ll; split_bf16(v, &hh, &ll);
    th[(size_t)hrow * 544 + kb + tx] = hh;
    tl[(size_t)hrow * 544 + kb + tx] = ll;
  }
}

// ---- split-bf16 MFMA NT GEMM (64x64 tile; round-8 showed 128-tiles regress:
// staging is L2-resident so bigger tiles only add reg/LDS pressure) ----
// PASSES=3: hi*hi + hi*lo + lo*hi (~fp32). PASSES=1: hi*hi only (~bf16) —
// used for G, whose only consumer is neighbor SELECTION.
// EPI=0: f32 C. EPI=1: zact epilogue -> bf16-split act. EPI=2: bf16-split C.
template <int EPI, int PASSES>
__global__ __launch_bounds__(256)
void mfma_nt(const unsigned short* __restrict__ Ah, const unsigned short* __restrict__ Al, int lda,
             const unsigned short* __restrict__ Bh, const unsigned short* __restrict__ Bl, int ldb,
             int K, float* __restrict__ C, int ldc,
             const float* __restrict__ b1, const float* __restrict__ W2,
             unsigned short* __restrict__ acth, unsigned short* __restrict__ actl) {
  __shared__ unsigned short sAh[64 * 40], sBh[64 * 40];
  __shared__ unsigned short sAl[PASSES == 3 ? 64 * 40 : 16];
  __shared__ unsigned short sBl[PASSES == 3 ? 64 * 40 : 16];
  const int tid = threadIdx.x;
  const int lane = tid & 63, wv = tid >> 6;
  const int wm = wv >> 1, wn = wv & 1;
  const int lr = lane & 15, lq = lane >> 4;
  const int m0 = blockIdx.y * 64, n0 = blockIdx.x * 64;
  const int srow = tid >> 2, sk = (tid & 3) * 8;
  f32x4 acc[2][2];
  #pragma unroll
  for (int mt = 0; mt < 2; mt++)
    #pragma unroll
    for (int nt = 0; nt < 2; nt++)
      #pragma unroll
      for (int i = 0; i < 4; i++) acc[mt][nt][i] = 0.f;

  for (int kb = 0; kb < K; kb += 32) {
    float4 va = *(const float4*)(Ah + (size_t)(m0 + srow) * lda + kb + sk);
    float4 vc = *(const float4*)(Bh + (size_t)(n0 + srow) * ldb + kb + sk);
    float4 vb, vd;
    if (PASSES == 3) {
      vb = *(const float4*)(Al + (size_t)(m0 + srow) * lda + kb + sk);
      vd = *(const float4*)(Bl + (size_t)(n0 + srow) * ldb + kb + sk);
    }
    __syncthreads();
    *(float4*)&sAh[srow * 40 + sk] = va;
    *(float4*)&sBh[srow * 40 + sk] = vc;
    if (PASSES == 3) {
      *(float4*)&sAl[srow * 40 + sk] = vb;
      *(float4*)&sBl[srow * 40 + sk] = vd;
    }
    __syncthreads();
    s16x8 fah[2], fal[2], fbh[2], fbl[2];
    #pragma unroll
    for (int mt = 0; mt < 2; mt++) {
      const int r = wm * 32 + mt * 16 + lr;
      fah[mt] = *(const s16x8*)&sAh[r * 40 + lq * 8];
      if (PASSES == 3) fal[mt] = *(const s16x8*)&sAl[r * 40 + lq * 8];
    }
    #pragma unroll
    for (int nt = 0; nt < 2; nt++) {
      const int r = wn * 32 + nt * 16 + lr;
      fbh[nt] = *(const s16x8*)&sBh[r * 40 + lq * 8];
      if (PASSES == 3) fbl[nt] = *(const s16x8*)&sBl[r * 40 + lq * 8];
    }
    #pragma unroll
    for (int mt = 0; mt < 2; mt++)
      #pragma unroll
      for (int nt = 0; nt < 2; nt++)
        acc[mt][nt] = __builtin_amdgcn_mfma_f32_16x16x32_bf16(fah[mt], fbh[nt], acc[mt][nt], 0, 0, 0);
    if (PASSES == 3) {
      #pragma unroll
      for (int mt = 0; mt < 2; mt++)
        #pragma unroll
        for (int nt = 0; nt < 2; nt++)
          acc[mt][nt] = __builtin_amdgcn_mfma_f32_16x16x32_bf16(fah[mt], fbl[nt], acc[mt][nt], 0, 0, 0);
      #pragma unroll
      for (int mt = 0; mt < 2; mt++)
        #pragma unroll
        for (int nt = 0; nt < 2; nt++)
          acc[mt][nt] = __builtin_amdgcn_mfma_f32_16x16x32_bf16(fal[mt], fbh[nt], acc[mt][nt], 0, 0, 0);
    }
  }

  // C/D layout: row=(lane>>4)*4+reg, col=lane&15  [verified m89/m91]
  #pragma unroll
  for (int nt = 0; nt < 2; nt++) {
    const int n = n0 + wn * 32 + nt * 16 + lr;
    float bb = 0.f, ww = 0.f;
    if (EPI == 1) { bb = b1[n]; ww = W2[n]; }
    #pragma unroll
    for (int mt = 0; mt < 2; mt++) {
      #pragma unroll
      for (int r = 0; r < 4; r++) {
        const int m = m0 + wm * 32 + mt * 16 + lq * 4 + r;
        float v = acc[mt][nt][r];
        if (EPI == 0) {
          C[(size_t)m * ldc + n] = v;
        } else if (EPI == 1) {
          float z = v + bb;
          float e = __builtin_amdgcn_exp2f(fabsf(z) * -2.885390082f);
          float rc = __builtin_amdgcn_rcpf(1.f + e);
          float s = 4.f * e * rc * rc * ww;
          unsigned short hh, ll; split_bf16(s, &hh, &ll);
          acth[(size_t)m * ldc + n] = hh;
          actl[(size_t)m * ldc + n] = ll;
        } else {
          unsigned short hh, ll; split_bf16(v, &hh, &ll);
          acth[(size_t)m * ldc + n] = hh;
          actl[(size_t)m * ldc + n] = ll;
        }
      }
    }
  }
}

// ---- batched S builder (K-slab, 4 blocks/CU) ----
// Sx[0:50][0:50] = neighbor Gram (pre-centering), Sx[50][0:50] = q_k.
__global__ __launch_bounds__(256)
void sbuild_kernel(const unsigned short* __restrict__ ph, const unsigned short* __restrict__ pl,
                   const unsigned short* __restrict__ gh, const unsigned short* __restrict__ gl,
                   const int* __restrict__ idx, float* __restrict__ Sx) {
  __shared__ unsigned short sh[64 * SROW];
  __shared__ unsigned short sl[64 * SROW];
  __shared__ int ids[K_];
  const int b = blockIdx.x;
  const int tid = threadIdx.x;
  if (tid < K_) ids[tid] = idx[b * K_ + tid];
  const int lane = tid & 63, wv = tid >> 6;
  const int wm = wv >> 1, wn = wv & 1;
  const int lr = lane & 15, lq = lane >> 4;
  const int strow = tid >> 4, stk = (tid & 15) * 8;
  __syncthreads();

  f32x4 acc[2][2];
  #pragma unroll
  for (int mt = 0; mt < 2; mt++)
    #pragma unroll
    for (int nt = 0; nt < 2; nt++)
      #pragma unroll
      for (int i = 0; i < 4; i++) acc[mt][nt][i] = 0.f;

  for (int kb = 0; kb < 512; kb += SLAB) {
    __syncthreads();
    #pragma unroll
    for (int p = 0; p < 4; p++) {
      const int r = p * 16 + strow;
      if (r < 51) {
        const unsigned short* srch = (r < 50) ? ph + (size_t)ids[r] * 512 : gh + (size_t)b * 512;
        const unsigned short* srcl = (r < 50) ? pl + (size_t)ids[r] * 512 : gl + (size_t)b * 512;
        *(float4*)&sh[r * SROW + stk] = *(const float4*)(srch + kb + stk);
        *(float4*)&sl[r * SROW + stk] = *(const float4*)(srcl + kb + stk);
      }
    }
    __syncthreads();
    #pragma unroll
    for (int kk = 0; kk < SLAB; kk += 32) {
      s16x8 fah[2], fal[2], fbh[2], fbl[2];
      #pragma unroll
      for (int mt = 0; mt < 2; mt++) {
        const int r = wm * 32 + mt * 16 + lr;
        fah[mt] = *(const s16x8*)&sh[r * SROW + kk + lq * 8];
        fal[mt] = *(const s16x8*)&sl[r * SROW + kk + lq * 8];
      }
      #pragma unroll
      for (int nt = 0; nt < 2; nt++) {
        const int r = wn * 32 + nt * 16 + lr;
        fbh[nt] = *(const s16x8*)&sh[r * SROW + kk + lq * 8];
        fbl[nt] = *(const s16x8*)&sl[r * SROW + kk + lq * 8];
      }
      #pragma unroll
      for (int mt = 0; mt < 2; mt++)
        #pragma unroll
        for (int nt = 0; nt < 2; nt++)
          acc[mt][nt] = __builtin_amdgcn_mfma_f32_16x16x32_bf16(fah[mt], fbh[nt], acc[mt][nt], 0, 0, 0);
      #pragma unroll
      for (int mt = 0; mt < 2; mt++)
        #pragma unroll
        for (int nt = 0; nt < 2; nt++)
          acc[mt][nt] = __builtin_amdgcn_mfma_f32_16x16x32_bf16(fah[mt], fbl[nt], acc[mt][nt], 0, 0, 0);
      #pragma unroll
      for (int mt = 0; mt < 2; mt++)
        #pragma unroll
        for (int nt = 0; nt < 2; nt++)
          acc[mt][nt] = __builtin_amdgcn_mfma_f32_16x16x32_bf16(fal[mt], fbh[nt], acc[mt][nt], 0, 0, 0);
    }
  }

  float* Sb = Sx + (size_t)b * SX_STRIDE;
  #pragma unroll
  for (int nt = 0; nt < 2; nt++) {
    const int n = wn * 32 + nt * 16 + lr;
    #pragma unroll
    for (int mt = 0; mt < 2; mt++) {
      #pragma unroll
      for (int r = 0; r < 4; r++) {
        const int m = wm * 32 + mt * 16 + lq * 4 + r;
        if (m < 51 && n < 52) Sb[m * 52 + n] = acc[mt][nt][r];
      }
    }
  }
}

// sq[b] = sum_d P[b,d]^2
__global__ __launch_bounds__(64)
void sq_kernel(const float* __restrict__ P, float* __restrict__ sq) {
  const int b = blockIdx.x, lane = threadIdx.x;
  const float* pr = P + (size_t)b * 512;
  float s = 0.f;
  #pragma unroll
  for (int i = 0; i < 8; i++) { float v = pr[lane + i * 64]; s += v * v; }
  s = bsum64(s);
  if (lane == 0) sq[b] = s;
}

// Per row b (one wave, barrier-free): 50 smallest of sq[j]-2*G[b,j]
__global__ __launch_bounds__(64)
void topk_kernel(const float* __restrict__ G, const float* __restrict__ sq,
                 int* __restrict__ idx) {
  const int b = blockIdx.x, lane = threadIdx.x;
  const float* row = G + (size_t)b * 2048;
  float v[32];
  #pragma unroll
  for (int i = 0; i < 32; i++) {
    const int j = i * 64 + lane;
    v[i] = sq[j] - 2.f * row[j];
  }
  float lmin = v[0]; int lslot = 0;
  #pragma unroll
  for (int i = 1; i < 32; i++) { if (v[i] < lmin) { lmin = v[i]; lslot = i; } }
  for (int it = 0; it < K_; it++) {
    float bv = lmin; int bl = lane, bs = lslot;
    #pragma unroll
    for (int o = 1; o < 64; o <<= 1) {
      float ov = __shfl_xor(bv, o);
      int ol = __shfl_xor(bl, o);
      int os = __shfl_xor(bs, o);
      if (ov < bv || (ov == bv && ol < bl)) { bv = ov; bl = ol; bs = os; }
    }
    if (lane == 0) idx[b * K_ + it] = bs * 64 + bl;
    if (lane == bl) {
      #pragma unroll
      for (int i = 0; i < 32; i++) if (i == bs) v[i] = FLT_MAX;
      lmin = v[0]; lslot = 0;
      #pragma unroll
      for (int i = 1; i < 32; i++) { if (v[i] < lmin) { lmin = v[i]; lslot = i; } }
    }
  }
}

// Per wave: TWO independent batches, statement-interleaved (round 11).
// Rationale: single-problem waves leave the CU's DS pipe ~55% idle (per-round
// serial chain: bpermute -> dot -> rotation -> update). Problem B's shuffles
// fill problem A's latency gaps. Same pair schedule m for both problems.
// Per-problem arithmetic order is identical to the single-problem version
// -> bit-identical output. 128-thr blocks, grid B/4, launch_bounds(128,1):
// VGPR cap 512 so fA+fB+yA+yB (~230 regs) never spill (round-2 lesson).
__global__ __launch_bounds__(128, 1)
void final_kernel(const float* __restrict__ Sx, float* __restrict__ out) {
  const int lane = threadIdx.x & 63;
  const int wid = threadIdx.x >> 6;
  const int bA = blockIdx.x * 4 + wid * 2;
  const int bB = bA + 1;
  const float* SbA = Sx + (size_t)bA * SX_STRIDE;
  const float* SbB = Sx + (size_t)bB * SX_STRIDE;

  float qA = (lane < K_) ? SbA[50 * 52 + lane] : 0.f;
  float qB = (lane < K_) ? SbB[50 * 52 + lane] : 0.f;
  float qmA = qA, qmB = qB;
  bsum64x2(qmA, qmB);
  float wA = (lane < K_) ? (qA - qmA * (1.f / K_)) : 0.f;
  float wB = (lane < K_) ? (qB - qmB * (1.f / K_)) : 0.f;

  float fA[K_], fB[K_];
  #pragma unroll
  for (int r = 0; r < K_; r++) {
    fA[r] = (lane < K_) ? SbA[r * 52 + lane] : 0.f;
    fB[r] = (lane < K_) ? SbB[r * 52 + lane] : 0.f;
  }

  // double-centering (rowmean==colmean by symmetry)
  float cmA = 0.f, cmB = 0.f;
  #pragma unroll
  for (int r = 0; r < K_; r++) { cmA += fA[r]; cmB += fB[r]; }
  cmA *= (1.f / K_); cmB *= (1.f / K_);
  float gsA = (lane < K_) ? cmA : 0.f;
  float gsB = (lane < K_) ? cmB : 0.f;
  bsum64x2(gsA, gsB);
  float csA = cmA - gsA * (1.f / K_);
  float csB = cmB - gsB * (1.f / K_);
  #pragma unroll
  for (int r = 0; r < K_; r++) {
    float rmA = __shfl(cmA, r);
    float rmB = __shfl(cmB, r);
    if (lane < K_) { fA[r] -= rmA + csA; fB[r] -= rmB + csB; }
  }

  float nrmA = 0.f, nrmB = 0.f;
  #pragma unroll
  for (int r = 0; r < K_; r++) { nrmA += fA[r] * fA[r]; nrmB += fB[r] * fB[r]; }

  for (int sweep = 0; sweep < NSWEEP; sweep++) {
    for (int r = 0; r < 49; r++) {
      const int kk = (25 * r) % 49;
      int m;
      if (lane >= K_)      m = lane;
      else if (lane == 49) m = kk;
      else if (lane == kk) m = 49;
      else { m = (r - lane) % 49; if (m < 0) m += 49; }

      float yA[K_], yB[K_];
      float a0 = 0.f, a1 = 0.f, b0 = 0.f, b1 = 0.f;
      #pragma unroll
      for (int r2 = 0; r2 < K_; r2 += 2) {
        yA[r2]     = __shfl(fA[r2], m);
        yB[r2]     = __shfl(fB[r2], m);
        yA[r2 + 1] = __shfl(fA[r2 + 1], m);
        yB[r2 + 1] = __shfl(fB[r2 + 1], m);
        a0 += fA[r2] * yA[r2];
        b0 += fB[r2] * yB[r2];
        a1 += fA[r2 + 1] * yA[r2 + 1];
        b1 += fB[r2 + 1] * yB[r2 + 1];
      }
      float dotA = a0 + a1;
      float dotB = b0 + b1;
      float onrmA = __shfl(nrmA, m);
      float onrmB = __shfl(nrmB, m);

      const bool isp = lane < m;
      float alA = isp ? nrmA : onrmA, beA = isp ? onrmA : nrmA;
      float alB = isp ? nrmB : onrmB, beB = isp ? onrmB : nrmB;
      float tauA = (beA - alA) * 0.5f * __builtin_amdgcn_rcpf(dotA);
      float tauB = (beB - alB) * 0.5f * __builtin_amdgcn_rcpf(dotB);
      float sgA = (tauA >= 0.f) ? 1.f : -1.f;
      float sgB = (tauB >= 0.f) ? 1.f : -1.f;
      float s1A = __builtin_amdgcn_sqrtf(1.f + tauA * tauA);
      float s1B = __builtin_amdgcn_sqrtf(1.f + tauB * tauB);
      float ttA = sgA * __builtin_amdgcn_rcpf(fabsf(tauA) + s1A);
      float ttB = sgB * __builtin_amdgcn_rcpf(fabsf(tauB) + s1B);
      float ccA = __builtin_amdgcn_rsqf(1.f + ttA * ttA);
      float ccB = __builtin_amdgcn_rsqf(1.f + ttB * ttB);
      float svA = ttA * ccA, svB = ttB * ccB;
      float srA = isp ? -svA : svA;
      float srB = isp ? -svB : svB;
      if (lane >= K_ || fabsf(dotA) < 1e-20f) { ccA = 1.f; srA = 0.f; }
      if (lane >= K_ || fabsf(dotB) < 1e-20f) { ccB = 1.f; srB = 0.f; }
      #pragma unroll
      for (int r2 = 0; r2 < K_; r2++) {
        fA[r2] = ccA * fA[r2] + srA * yA[r2];
        fB[r2] = ccB * fB[r2] + srB * yB[r2];
      }
      float ywA = __shfl(wA, m);
      float ywB = __shfl(wB, m);
      wA = ccA * wA + srA * ywA;
      wB = ccB * wB + srB * ywB;
      nrmA = ccA * ccA * nrmA + srA * srA * onrmA + 2.f * ccA * srA * dotA;
      nrmB = ccB * ccB * nrmB + srB * srB * onrmB + 2.f * ccB * srB * dotB;
    }
  }

  float n2A = 0.f, n2B = 0.f;
  #pragma unroll
  for (int r2 = 0; r2 < K_; r2++) { n2A += fA[r2] * fA[r2]; n2B += fB[r2] * fB[r2]; }
  int rkA = 0, rkB = 0;
  #pragma unroll
  for (int j = 0; j < K_; j++) {
    float vjA = __shfl(n2A, j);
    float vjB = __shfl(n2B, j);
    rkA += (vjA > n2A || (vjA == n2A && j < lane)) ? 1 : 0;
    rkB += (vjB > n2B || (vjB == n2B && j < lane)) ? 1 : 0;
  }
  float cA = (lane < K_ && rkA < M_) ? (wA * wA / sqrtf(n2A)) : 0.f;
  float cB = (lane < K_ && rkB < M_) ? (wB * wB / sqrtf(n2B)) : 0.f;
  float contrib = bsum64(cA + cB);
  if (lane == 0) atomicAdd(out, contrib * (1.f / B_));
}

extern "C" void kernel_launch(void* const* d_in, const int* in_sizes, int n_in,
                              void* d_out, int out_size, void* d_ws, size_t ws_size,
                              hipStream_t stream) {
  const float* x  = (const float*)d_in[0];
  const float* t  = (const float*)d_in[1];
  const float* P  = (const float*)d_in[2];
  const float* W1 = (const float*)d_in[3];
  const float* b1 = (const float*)d_in[4];
  const float* W2 = (const float*)d_in[5];
  // d_in[6] = b2: does not affect the gradient; unused.
  float* out = (float*)d_out;

  // workspace layout (~43 MB). Sx aliases G (dead after topk) + xt/w1t (dead
  // after the zact GEMM) — safe because sbuild runs after all of them.
  float* G    = (float*)d_ws;                         // 2048*2048 f32 (16 MB)
  float* Sx   = (float*)d_ws;                         // alias (21.7 MB)
  unsigned short* xt_h  = (unsigned short*)(G + (size_t)B_ * B_);  // [2048][544]
  unsigned short* xt_l  = xt_h  + (size_t)B_ * 544;
  unsigned short* w1t_h = xt_l  + (size_t)B_ * 544;   // [1024][544]
  unsigned short* w1t_l = w1t_h + (size_t)H_ * 544;
  unsigned short* w1_h  = w1t_l + (size_t)H_ * 544;   // [528][1024]
  unsigned short* w1_l  = w1_h  + (size_t)528 * H_;
  unsigned short* p_h   = w1_l  + (size_t)528 * H_;   // [2048][512]
  unsigned short* p_l   = p_h   + (size_t)B_ * D_;
  unsigned short* act_h = p_l   + (size_t)B_ * D_;    // [2048][1024]
  unsigned short* act_l = act_h + (size_t)B_ * H_;
  unsigned short* g_h   = act_l + (size_t)B_ * H_;    // [2048][512]
  unsigned short* g_l   = g_h   + (size_t)B_ * D_;
  float* sq   = (float*)(g_l + (size_t)B_ * D_);      // 2048
  int*   idx  = (int*)(sq + B_);                      // 2048*50

  hipMemsetAsync(d_out, 0, sizeof(float), stream);

  // bf16 hi/lo conversions
  conv_xt<<<dim3(3, B_), 256, 0, stream>>>(x, t, xt_h, xt_l);
  conv_w1t<<<dim3(17, 32), 256, 0, stream>>>(W1, w1t_h, w1t_l);
  conv_mat<<<(528 * H_ + 255) / 256, 256, 0, stream>>>(W1, w1_h, w1_l, 528 * H_);
  conv_mat<<<(B_ * D_ + 255) / 256, 256, 0, stream>>>(P, p_h, p_l, B_ * D_);

  // act = sech^2(xt@W1 + b1) * W2   (3-pass, bf16-split output, fused epilogue)
  mfma_nt<1, 3><<<dim3(H_ / 64, B_ / 64), 256, 0, stream>>>(
      xt_h, xt_l, 544, w1t_h, w1t_l, 544, 544,
      nullptr, H_, b1, W2, act_h, act_l);
  // grad[b,d] = sum_h act[b,h] * W1[d,h]  (3-pass -> bf16-split output)
  mfma_nt<2, 3><<<dim3(D_ / 64, B_ / 64), 256, 0, stream>>>(
      act_h, act_l, H_, w1_h, w1_l, H_, H_,
      nullptr, D_, nullptr, nullptr, g_h, g_l);
  // G = P @ P^T  (1-pass hi-only: selection-grade precision is sufficient)
  mfma_nt<0, 1><<<dim3(B_ / 64, B_ / 64), 256, 0, stream>>>(
      p_h, nullptr, D_, p_h, nullptr, D_, D_,
      G, B_, nullptr, nullptr, nullptr, nullptr);

  sq_kernel<<<B_, 64, 0, stream>>>(P, sq);
  topk_kernel<<<B_, 64, 0, stream>>>(G, sq, idx);
  sbuild_kernel<<<B_, 256, 0, stream>>>(p_h, p_l, g_h, g_l, idx, Sx);
  // dual-batch interleaved spectral projection (2 batches/wave, 4/block)
  final_kernel<<<B_ / 4, 128, 0, stream>>>(Sx, out);
}

// Round 12
// 290.435 us; speedup vs baseline: 1.1351x; 1.1351x over previous
//
#include <hip/hip_runtime.h>
#include <math.h>
#include <float.h>

// Problem constants (match reference)
#define B_ 2048
#define D_ 512
#define T_ 16
#define H_ 1024
#define K_ 50
#define M_ 16
#define NSWEEP 1      // validated rounds 9/10: absmax 6.1e-5 vs 2.65e-4 threshold
#define SX_STRIDE 2656  // floats per batch in Sx ([51 rows][52 cols] + pad, 16B aligned)
#define SLAB 128        // sbuild K-slab width (shorts)
#define SROW 136        // sbuild LDS row stride in shorts
#define FS 52           // final_kernel LDS column stride (words): 16B-aligned, 2-way-free banks

typedef __attribute__((ext_vector_type(8))) short s16x8;   // 8 bf16 (4 VGPRs)
typedef __attribute__((ext_vector_type(4))) float f32x4;   // MFMA accumulator

__device__ __forceinline__ float bsum64(float v) {
  #pragma unroll
  for (int o = 1; o < 64; o <<= 1) v += __shfl_xor(v, o);
  return v;
}

// ---- bf16 split helpers (RNE) ----
__device__ __forceinline__ unsigned bf16_rne(float v) {
  union { float f; unsigned u; } a; a.f = v;
  return (a.u + 0x7FFFu + ((a.u >> 16) & 1u)) >> 16;
}
__device__ __forceinline__ float bf16_val(unsigned h) {
  union { unsigned u; float f; } a; a.u = h << 16;
  return a.f;
}
__device__ __forceinline__ void split_bf16(float v, unsigned short* h, unsigned short* l) {
  unsigned hh = bf16_rne(v);
  *h = (unsigned short)hh;
  *l = (unsigned short)bf16_rne(v - bf16_val(hh));
}

// ---- conversion kernels ----
// xt[b, 0:512]=x, [512:528]=t, [528:544]=0   (K padded to 544 = 17*32)
__global__ __launch_bounds__(256)
void conv_xt(const float* __restrict__ x, const float* __restrict__ t,
             unsigned short* __restrict__ xh, unsigned short* __restrict__ xl) {
  const int b = blockIdx.y;
  const int c = blockIdx.x * 256 + threadIdx.x;
  if (c >= 544) return;
  float v = 0.f;
  if (c < 512) v = x[(size_t)b * 512 + c];
  else if (c < 528) v = t[(size_t)b * 16 + (c - 512)];
  unsigned short hh, ll; split_bf16(v, &hh, &ll);
  xh[(size_t)b * 544 + c] = hh;
  xl[(size_t)b * 544 + c] = ll;
}

// straight element-wise split (W1 and P)
__global__ __launch_bounds__(256)
void conv_mat(const float* __restrict__ A, unsigned short* __restrict__ h,
              unsigned short* __restrict__ l, int n) {
  int i = blockIdx.x * 256 + threadIdx.x;
  if (i >= n) return;
  unsigned short hh, ll; split_bf16(A[i], &hh, &ll);
  h[i] = hh; l[i] = ll;
}

// w1t[h, k] = W1[k, h], k padded 528->544 with zeros.  32x32 LDS tile transpose.
__global__ __launch_bounds__(256)
void conv_w1t(const float* __restrict__ W1, unsigned short* __restrict__ th,
              unsigned short* __restrict__ tl) {
  __shared__ float tile[32][33];
  const int tx = threadIdx.x & 31, ty = threadIdx.x >> 5;   // 32 x 8
  const int kb = blockIdx.x * 32, hb = blockIdx.y * 32;
  #pragma unroll
  for (int j = 0; j < 4; j++) {
    int k = kb + ty + j * 8;
    tile[ty + j * 8][tx] = (k < 528) ? W1[(size_t)k * 1024 + hb + tx] : 0.f;
  }
  __syncthreads();
  #pragma unroll
  for (int j = 0; j < 4; j++) {
    int hrow = hb + ty + j * 8;
    float v = tile[tx][ty + j * 8];
    unsigned short hh, ll; split_bf16(v, &hh, &ll);
    th[(size_t)hrow * 544 + kb + tx] = hh;
    tl[(size_t)hrow * 544 + kb + tx] = ll;
  }
}

// ---- split-bf16 MFMA NT GEMM (64x64 tile; round-8 showed 128-tiles regress:
// staging is L2-resident so bigger tiles only add reg/LDS pressure) ----
// PASSES=3: hi*hi + hi*lo + lo*hi (~fp32). PASSES=1: hi*hi only (~bf16) —
// used for G, whose only consumer is neighbor SELECTION.
// EPI=0: f32 C. EPI=1: zact epilogue -> bf16-split act. EPI=2: bf16-split C.
template <int EPI, int PASSES>
__global__ __launch_bounds__(256)
void mfma_nt(const unsigned short* __restrict__ Ah, const unsigned short* __restrict__ Al, int lda,
             const unsigned short* __restrict__ Bh, const unsigned short* __restrict__ Bl, int ldb,
             int K, float* __restrict__ C, int ldc,
             const float* __restrict__ b1, const float* __restrict__ W2,
             unsigned short* __restrict__ acth, unsigned short* __restrict__ actl) {
  __shared__ unsigned short sAh[64 * 40], sBh[64 * 40];
  __shared__ unsigned short sAl[PASSES == 3 ? 64 * 40 : 16];
  __shared__ unsigned short sBl[PASSES == 3 ? 64 * 40 : 16];
  const int tid = threadIdx.x;
  const int lane = tid & 63, wv = tid >> 6;
  const int wm = wv >> 1, wn = wv & 1;
  const int lr = lane & 15, lq = lane >> 4;
  const int m0 = blockIdx.y * 64, n0 = blockIdx.x * 64;
  const int srow = tid >> 2, sk = (tid & 3) * 8;
  f32x4 acc[2][2];
  #pragma unroll
  for (int mt = 0; mt < 2; mt++)
    #pragma unroll
    for (int nt = 0; nt < 2; nt++)
      #pragma unroll
      for (int i = 0; i < 4; i++) acc[mt][nt][i] = 0.f;

  for (int kb = 0; kb < K; kb += 32) {
    float4 va = *(const float4*)(Ah + (size_t)(m0 + srow) * lda + kb + sk);
    float4 vc = *(const float4*)(Bh + (size_t)(n0 + srow) * ldb + kb + sk);
    float4 vb, vd;
    if (PASSES == 3) {
      vb = *(const float4*)(Al + (size_t)(m0 + srow) * lda + kb + sk);
      vd = *(const float4*)(Bl + (size_t)(n0 + srow) * ldb + kb + sk);
    }
    __syncthreads();
    *(float4*)&sAh[srow * 40 + sk] = va;
    *(float4*)&sBh[srow * 40 + sk] = vc;
    if (PASSES == 3) {
      *(float4*)&sAl[srow * 40 + sk] = vb;
      *(float4*)&sBl[srow * 40 + sk] = vd;
    }
    __syncthreads();
    s16x8 fah[2], fal[2], fbh[2], fbl[2];
    #pragma unroll
    for (int mt = 0; mt < 2; mt++) {
      const int r = wm * 32 + mt * 16 + lr;
      fah[mt] = *(const s16x8*)&sAh[r * 40 + lq * 8];
      if (PASSES == 3) fal[mt] = *(const s16x8*)&sAl[r * 40 + lq * 8];
    }
    #pragma unroll
    for (int nt = 0; nt < 2; nt++) {
      const int r = wn * 32 + nt * 16 + lr;
      fbh[nt] = *(const s16x8*)&sBh[r * 40 + lq * 8];
      if (PASSES == 3) fbl[nt] = *(const s16x8*)&sBl[r * 40 + lq * 8];
    }
    #pragma unroll
    for (int mt = 0; mt < 2; mt++)
      #pragma unroll
      for (int nt = 0; nt < 2; nt++)
        acc[mt][nt] = __builtin_amdgcn_mfma_f32_16x16x32_bf16(fah[mt], fbh[nt], acc[mt][nt], 0, 0, 0);
    if (PASSES == 3) {
      #pragma unroll
      for (int mt = 0; mt < 2; mt++)
        #pragma unroll
        for (int nt = 0; nt < 2; nt++)
          acc[mt][nt] = __builtin_amdgcn_mfma_f32_16x16x32_bf16(fah[mt], fbl[nt], acc[mt][nt], 0, 0, 0);
      #pragma unroll
      for (int mt = 0; mt < 2; mt++)
        #pragma unroll
        for (int nt = 0; nt < 2; nt++)
          acc[mt][nt] = __builtin_amdgcn_mfma_f32_16x16x32_bf16(fal[mt], fbh[nt], acc[mt][nt], 0, 0, 0);
    }
  }

  // C/D layout: row=(lane>>4)*4+reg, col=lane&15  [verified m89/m91]
  #pragma unroll
  for (int nt = 0; nt < 2; nt++) {
    const int n = n0 + wn * 32 + nt * 16 + lr;
    float bb = 0.f, ww = 0.f;
    if (EPI == 1) { bb = b1[n]; ww = W2[n]; }
    #pragma unroll
    for (int mt = 0; mt < 2; mt++) {
      #pragma unroll
      for (int r = 0; r < 4; r++) {
        const int m = m0 + wm * 32 + mt * 16 + lq * 4 + r;
        float v = acc[mt][nt][r];
        if (EPI == 0) {
          C[(size_t)m * ldc + n] = v;
        } else if (EPI == 1) {
          float z = v + bb;
          float e = __builtin_amdgcn_exp2f(fabsf(z) * -2.885390082f);
          float rc = __builtin_amdgcn_rcpf(1.f + e);
          float s = 4.f * e * rc * rc * ww;
          unsigned short hh, ll; split_bf16(s, &hh, &ll);
          acth[(size_t)m * ldc + n] = hh;
          actl[(size_t)m * ldc + n] = ll;
        } else {
          unsigned short hh, ll; split_bf16(v, &hh, &ll);
          acth[(size_t)m * ldc + n] = hh;
          actl[(size_t)m * ldc + n] = ll;
        }
      }
    }
  }
}

// ---- batched S builder (K-slab, 4 blocks/CU) ----
// Sx[0:50][0:50] = neighbor Gram (pre-centering), Sx[50][0:50] = q_k.
__global__ __launch_bounds__(256)
void sbuild_kernel(const unsigned short* __restrict__ ph, const unsigned short* __restrict__ pl,
                   const unsigned short* __restrict__ gh, const unsigned short* __restrict__ gl,
                   const int* __restrict__ idx, float* __restrict__ Sx) {
  __shared__ unsigned short sh[64 * SROW];
  __shared__ unsigned short sl[64 * SROW];
  __shared__ int ids[K_];
  const int b = blockIdx.x;
  const int tid = threadIdx.x;
  if (tid < K_) ids[tid] = idx[b * K_ + tid];
  const int lane = tid & 63, wv = tid >> 6;
  const int wm = wv >> 1, wn = wv & 1;
  const int lr = lane & 15, lq = lane >> 4;
  const int strow = tid >> 4, stk = (tid & 15) * 8;
  __syncthreads();

  f32x4 acc[2][2];
  #pragma unroll
  for (int mt = 0; mt < 2; mt++)
    #pragma unroll
    for (int nt = 0; nt < 2; nt++)
      #pragma unroll
      for (int i = 0; i < 4; i++) acc[mt][nt][i] = 0.f;

  for (int kb = 0; kb < 512; kb += SLAB) {
    __syncthreads();
    #pragma unroll
    for (int p = 0; p < 4; p++) {
      const int r = p * 16 + strow;
      if (r < 51) {
        const unsigned short* srch = (r < 50) ? ph + (size_t)ids[r] * 512 : gh + (size_t)b * 512;
        const unsigned short* srcl = (r < 50) ? pl + (size_t)ids[r] * 512 : gl + (size_t)b * 512;
        *(float4*)&sh[r * SROW + stk] = *(const float4*)(srch + kb + stk);
        *(float4*)&sl[r * SROW + stk] = *(const float4*)(srcl + kb + stk);
      }
    }
    __syncthreads();
    #pragma unroll
    for (int kk = 0; kk < SLAB; kk += 32) {
      s16x8 fah[2], fal[2], fbh[2], fbl[2];
      #pragma unroll
      for (int mt = 0; mt < 2; mt++) {
        const int r = wm * 32 + mt * 16 + lr;
        fah[mt] = *(const s16x8*)&sh[r * SROW + kk + lq * 8];
        fal[mt] = *(const s16x8*)&sl[r * SROW + kk + lq * 8];
      }
      #pragma unroll
      for (int nt = 0; nt < 2; nt++) {
        const int r = wn * 32 + nt * 16 + lr;
        fbh[nt] = *(const s16x8*)&sh[r * SROW + kk + lq * 8];
        fbl[nt] = *(const s16x8*)&sl[r * SROW + kk + lq * 8];
      }
      #pragma unroll
      for (int mt = 0; mt < 2; mt++)
        #pragma unroll
        for (int nt = 0; nt < 2; nt++)
          acc[mt][nt] = __builtin_amdgcn_mfma_f32_16x16x32_bf16(fah[mt], fbh[nt], acc[mt][nt], 0, 0, 0);
      #pragma unroll
      for (int mt = 0; mt < 2; mt++)
        #pragma unroll
        for (int nt = 0; nt < 2; nt++)
          acc[mt][nt] = __builtin_amdgcn_mfma_f32_16x16x32_bf16(fah[mt], fbl[nt], acc[mt][nt], 0, 0, 0);
      #pragma unroll
      for (int mt = 0; mt < 2; mt++)
        #pragma unroll
        for (int nt = 0; nt < 2; nt++)
          acc[mt][nt] = __builtin_amdgcn_mfma_f32_16x16x32_bf16(fal[mt], fbh[nt], acc[mt][nt], 0, 0, 0);
    }
  }

  float* Sb = Sx + (size_t)b * SX_STRIDE;
  #pragma unroll
  for (int nt = 0; nt < 2; nt++) {
    const int n = wn * 32 + nt * 16 + lr;
    #pragma unroll
    for (int mt = 0; mt < 2; mt++) {
      #pragma unroll
      for (int r = 0; r < 4; r++) {
        const int m = wm * 32 + mt * 16 + lq * 4 + r;
        if (m < 51 && n < 52) Sb[m * 52 + n] = acc[mt][nt][r];
      }
    }
  }
}

// sq[b] = sum_d P[b,d]^2
__global__ __launch_bounds__(64)
void sq_kernel(const float* __restrict__ P, float* __restrict__ sq) {
  const int b = blockIdx.x, lane = threadIdx.x;
  const float* pr = P + (size_t)b * 512;
  float s = 0.f;
  #pragma unroll
  for (int i = 0; i < 8; i++) { float v = pr[lane + i * 64]; s += v * v; }
  s = bsum64(s);
  if (lane == 0) sq[b] = s;
}

// monotonic float->uint map (unsigned compare == float compare)
__device__ __forceinline__ unsigned fkey(float f) {
  unsigned u = __float_as_uint(f);
  return u ^ ((unsigned)((int)u >> 31) | 0x80000000u);
}

// Per row b (one wave, barrier-free): 50 smallest of sq[j]-2*G[b,j].
// 64-bit packed (value,index) keys: butterfly argmin is 12 DS ops/iter (was 18).
__global__ __launch_bounds__(64)
void topk_kernel(const float* __restrict__ G, const float* __restrict__ sq,
                 int* __restrict__ idx) {
  const int b = blockIdx.x, lane = threadIdx.x;
  const float* row = G + (size_t)b * 2048;
  float v[32];
  #pragma unroll
  for (int i = 0; i < 32; i++) {
    const int j = i * 64 + lane;
    v[i] = sq[j] - 2.f * row[j];
  }
  float lmin = v[0]; int lslot = 0;
  #pragma unroll
  for (int i = 1; i < 32; i++) { if (v[i] < lmin) { lmin = v[i]; lslot = i; } }
  unsigned long long lk = ((unsigned long long)fkey(lmin) << 11) | (unsigned)(lslot * 64 + lane);
  for (int it = 0; it < K_; it++) {
    unsigned long long bk = lk;
    #pragma unroll
    for (int o = 1; o < 64; o <<= 1) {
      unsigned long long ok = __shfl_xor(bk, o);
      if (ok < bk) bk = ok;
    }
    const int j = (int)(bk & 0x7FFu);
    if (lane == 0) idx[b * K_ + it] = j;
    if (lane == (j & 63)) {
      v[j >> 6] = FLT_MAX;
      lmin = v[0]; lslot = 0;
      #pragma unroll
      for (int i = 1; i < 32; i++) { if (v[i] < lmin) { lmin = v[i]; lslot = i; } }
      lk = ((unsigned long long)fkey(lmin) << 11) | (unsigned)(lslot * 64 + lane);
    }
  }
}

// Per batch (one wave): read precomputed Sx (coalesced), double-center, one-sided
// Jacobi. Round 12: column exchange via LDS b128 (13 reads + 13 writes per
// round) instead of 52 bpermutes — bpermute measured ~12 cyc/instr (round 11),
// so vector LDS moves 4x the bytes per instruction. Column slot = [f0..f49,
// nrm, w] (52 words, 16B-aligned; partner slots lane-consecutive -> 2 banks
// touches/bank per quarter-wave = free). Single wave => wave-synchronous, no
// barriers. Arithmetic order identical to round 10 -> bit-identical output.
__global__ __launch_bounds__(64, 2)
void final_kernel(const float* __restrict__ Sx, float* __restrict__ out) {
  __shared__ float cols[64 * FS];   // 13312 B; 8 blocks/CU -> 106 KB of 160 KB
  const int b = blockIdx.x;
  const int lane = threadIdx.x;
  const float* Sb = Sx + (size_t)b * SX_STRIDE;

  float q = (lane < K_) ? Sb[50 * 52 + lane] : 0.f;
  float qm = bsum64(q) * (1.f / K_);
  float w = (lane < K_) ? (q - qm) : 0.f;

  float f[K_];
  #pragma unroll
  for (int r = 0; r < K_; r++)
    f[r] = (lane < K_) ? Sb[r * 52 + lane] : 0.f;

  // double-centering (rowmean==colmean by symmetry)
  float cm = 0.f;
  #pragma unroll
  for (int r = 0; r < K_; r++) cm += f[r];
  cm *= (1.f / K_);
  float gs = bsum64(lane < K_ ? cm : 0.f) * (1.f / K_);
  float cs = cm - gs;
  #pragma unroll
  for (int r = 0; r < K_; r++) {
    float rm = __shfl(cm, r);
    if (lane < K_) f[r] -= rm + cs;
  }

  float nrm = 0.f;
  #pragma unroll
  for (int r = 0; r < K_; r++) nrm += f[r] * f[r];

  // publish own column to LDS: words 0..49 = f, 50 = nrm, 51 = w
  float* my = &cols[lane * FS];
  #pragma unroll
  for (int k = 0; k < 12; k++) {
    float4 t = {f[4 * k], f[4 * k + 1], f[4 * k + 2], f[4 * k + 3]};
    *(float4*)&my[4 * k] = t;
  }
  {
    float4 t = {f[48], f[49], nrm, w};
    *(float4*)&my[48] = t;
  }

  for (int sweep = 0; sweep < NSWEEP; sweep++) {
    for (int r = 0; r < 49; r++) {
      const int kk = (25 * r) % 49;
      int m;
      if (lane >= K_)      m = lane;
      else if (lane == 49) m = kk;
      else if (lane == kk) m = 49;
      else { m = (r - lane) % 49; if (m < 0) m += 49; }

      // partner column (+ nrm, w) via 13 vector LDS reads
      const float* pc = &cols[m * FS];
      float y[52];
      #pragma unroll
      for (int k = 0; k < 13; k++) {
        float4 t = *(const float4*)&pc[4 * k];
        y[4 * k] = t.x; y[4 * k + 1] = t.y; y[4 * k + 2] = t.z; y[4 * k + 3] = t.w;
      }
      float onrm = y[50];
      float yw   = y[51];

      float d0 = 0.f, d1 = 0.f, d2 = 0.f, d3 = 0.f;
      #pragma unroll
      for (int r2 = 0; r2 < 48; r2 += 4) {
        d0 += f[r2] * y[r2];
        d1 += f[r2 + 1] * y[r2 + 1];
        d2 += f[r2 + 2] * y[r2 + 2];
        d3 += f[r2 + 3] * y[r2 + 3];
      }
      d0 += f[48] * y[48];
      d1 += f[49] * y[49];
      float dot = (d0 + d1) + (d2 + d3);

      const bool isp = lane < m;
      float alpha = isp ? nrm : onrm;
      float beta  = isp ? onrm : nrm;
      float tau = (beta - alpha) * 0.5f * __builtin_amdgcn_rcpf(dot);
      float sg = (tau >= 0.f) ? 1.f : -1.f;
      float s1 = __builtin_amdgcn_sqrtf(1.f + tau * tau);
      float tt = sg * __builtin_amdgcn_rcpf(fabsf(tau) + s1);
      float cc = __builtin_amdgcn_rsqf(1.f + tt * tt);
      float ssv = tt * cc;
      float sr = isp ? -ssv : ssv;
      if (lane >= K_ || fabsf(dot) < 1e-20f) { cc = 1.f; sr = 0.f; }
      #pragma unroll
      for (int r2 = 0; r2 < K_; r2++) f[r2] = cc * f[r2] + sr * y[r2];
      w = cc * w + sr * yw;
      nrm = cc * cc * nrm + sr * sr * onrm + 2.f * cc * sr * dot;

      // publish updated column (reads of this round completed before f was
      // ready, so these writes cannot overtake them; next round's reads are
      // ordered after these writes by LDS RAW dependency)
      #pragma unroll
      for (int k = 0; k < 12; k++) {
        float4 t = {f[4 * k], f[4 * k + 1], f[4 * k + 2], f[4 * k + 3]};
        *(float4*)&my[4 * k] = t;
      }
      float4 t = {f[48], f[49], nrm, w};
      *(float4*)&my[48] = t;
    }
  }

  float n2 = 0.f;
  #pragma unroll
  for (int r2 = 0; r2 < K_; r2++) n2 += f[r2] * f[r2];
  int rank = 0;
  #pragma unroll
  for (int j = 0; j < K_; j++) {
    float vj = __shfl(n2, j);
    rank += (vj > n2 || (vj == n2 && j < lane)) ? 1 : 0;
  }
  float lam = sqrtf(n2);
  float contrib = (lane < K_ && rank < M_) ? (w * w / lam) : 0.f;
  contrib = bsum64(contrib);
  if (lane == 0) atomicAdd(out, contrib * (1.f / B_));
}

extern "C" void kernel_launch(void* const* d_in, const int* in_sizes, int n_in,
                              void* d_out, int out_size, void* d_ws, size_t ws_size,
                              hipStream_t stream) {
  const float* x  = (const float*)d_in[0];
  const float* t  = (const float*)d_in[1];
  const float* P  = (const float*)d_in[2];
  const float* W1 = (const float*)d_in[3];
  const float* b1 = (const float*)d_in[4];
  const float* W2 = (const float*)d_in[5];
  // d_in[6] = b2: does not affect the gradient; unused.
  float* out = (float*)d_out;

  // workspace layout (~43 MB). Sx aliases G (dead after topk) + xt/w1t (dead
  // after the zact GEMM) — safe because sbuild runs after all of them.
  float* G    = (float*)d_ws;                         // 2048*2048 f32 (16 MB)
  float* Sx   = (float*)d_ws;                         // alias (21.7 MB)
  unsigned short* xt_h  = (unsigned short*)(G + (size_t)B_ * B_);  // [2048][544]
  unsigned short* xt_l  = xt_h  + (size_t)B_ * 544;
  unsigned short* w1t_h = xt_l  + (size_t)B_ * 544;   // [1024][544]
  unsigned short* w1t_l = w1t_h + (size_t)H_ * 544;
  unsigned short* w1_h  = w1t_l + (size_t)H_ * 544;   // [528][1024]
  unsigned short* w1_l  = w1_h  + (size_t)528 * H_;
  unsigned short* p_h   = w1_l  + (size_t)528 * H_;   // [2048][512]
  unsigned short* p_l   = p_h   + (size_t)B_ * D_;
  unsigned short* act_h = p_l   + (size_t)B_ * D_;    // [2048][1024]
  unsigned short* act_l = act_h + (size_t)B_ * H_;
  unsigned short* g_h   = act_l + (size_t)B_ * H_;    // [2048][512]
  unsigned short* g_l   = g_h   + (size_t)B_ * D_;
  float* sq   = (float*)(g_l + (size_t)B_ * D_);      // 2048
  int*   idx  = (int*)(sq + B_);                      // 2048*50

  hipMemsetAsync(d_out, 0, sizeof(float), stream);

  // bf16 hi/lo conversions
  conv_xt<<<dim3(3, B_), 256, 0, stream>>>(x, t, xt_h, xt_l);
  conv_w1t<<<dim3(17, 32), 256, 0, stream>>>(W1, w1t_h, w1t_l);
  conv_mat<<<(528 * H_ + 255) / 256, 256, 0, stream>>>(W1, w1_h, w1_l, 528 * H_);
  conv_mat<<<(B_ * D_ + 255) / 256, 256, 0, stream>>>(P, p_h, p_l, B_ * D_);

  // act = sech^2(xt@W1 + b1) * W2   (3-pass, bf16-split output, fused epilogue)
  mfma_nt<1, 3><<<dim3(H_ / 64, B_ / 64), 256, 0, stream>>>(
      xt_h, xt_l, 544, w1t_h, w1t_l, 544, 544,
      nullptr, H_, b1, W2, act_h, act_l);
  // grad[b,d] = sum_h act[b,h] * W1[d,h]  (3-pass -> bf16-split output)
  mfma_nt<2, 3><<<dim3(D_ / 64, B_ / 64), 256, 0, stream>>>(
      act_h, act_l, H_, w1_h, w1_l, H_, H_,
      nullptr, D_, nullptr, nullptr, g_h, g_l);
  // G = P @ P^T  (1-pass hi-only: selection-grade precision is sufficient)
  mfma_nt<0, 1><<<dim3(B_ / 64, B_ / 64), 256, 0, stream>>>(
      p_h, nullptr, D_, p_h, nullptr, D_, D_,
      G, B_, nullptr, nullptr, nullptr, nullptr);

  sq_kernel<<<B_, 64, 0, stream>>>(P, sq);
  topk_kernel<<<B_, 64, 0, stream>>>(G, sq, idx);
  sbuild_kernel<<<B_, 256, 0, stream>>>(p_h, p_l, g_h, g_l, idx, Sx);
  final_kernel<<<B_, 64, 0, stream>>>(Sx, out);
}

// Round 13
// 257.904 us; speedup vs baseline: 1.2783x; 1.1261x over previous
//
#include <hip/hip_runtime.h>
#include <math.h>
#include <float.h>

// Problem constants (match reference)
#define B_ 2048
#define D_ 512
#define T_ 16
#define H_ 1024
#define K_ 50
#define M_ 16
#define NSWEEP 1      // validated rounds 9/10/12: absmax 6.1e-5..1.8e-4 vs 2.65e-4 threshold
#define SX_STRIDE 2656  // floats per batch in Sx ([51 rows][52 cols] + pad, 16B aligned)
#define SLAB 128        // sbuild K-slab width (shorts)
#define SROW 136        // sbuild LDS row stride in shorts
#define FS 52           // final_kernel LDS column stride (words)

typedef __attribute__((ext_vector_type(8))) short s16x8;   // 8 bf16 (4 VGPRs)
typedef __attribute__((ext_vector_type(4))) float f32x4;   // MFMA accumulator

__device__ __forceinline__ float bsum64(float v) {
  #pragma unroll
  for (int o = 1; o < 64; o <<= 1) v += __shfl_xor(v, o);
  return v;
}

// ---- bf16 split helpers (RNE) ----
__device__ __forceinline__ unsigned bf16_rne(float v) {
  union { float f; unsigned u; } a; a.f = v;
  return (a.u + 0x7FFFu + ((a.u >> 16) & 1u)) >> 16;
}
__device__ __forceinline__ float bf16_val(unsigned h) {
  union { unsigned u; float f; } a; a.u = h << 16;
  return a.f;
}
__device__ __forceinline__ void split_bf16(float v, unsigned short* h, unsigned short* l) {
  unsigned hh = bf16_rne(v);
  *h = (unsigned short)hh;
  *l = (unsigned short)bf16_rne(v - bf16_val(hh));
}

// ---- prep: per batch row, fused xt-split + P-split + sq reduce ----
// xt[b, 0:512]=x, [512:528]=t, [528:544]=0   (K padded to 544 = 17*32)
__global__ __launch_bounds__(256)
void prep_rows(const float* __restrict__ x, const float* __restrict__ t,
               const float* __restrict__ P,
               unsigned short* __restrict__ xh, unsigned short* __restrict__ xl,
               unsigned short* __restrict__ ph, unsigned short* __restrict__ pl,
               float* __restrict__ sq) {
  const int b = blockIdx.x, tid = threadIdx.x;
  for (int c = tid; c < 544; c += 256) {
    float v = 0.f;
    if (c < 512) v = x[(size_t)b * 512 + c];
    else if (c < 528) v = t[(size_t)b * 16 + (c - 512)];
    unsigned short hh, ll; split_bf16(v, &hh, &ll);
    xh[(size_t)b * 544 + c] = hh;
    xl[(size_t)b * 544 + c] = ll;
  }
  float s = 0.f;
  for (int c = tid; c < 512; c += 256) {
    float v = P[(size_t)b * 512 + c];
    s += v * v;
    unsigned short hh, ll; split_bf16(v, &hh, &ll);
    ph[(size_t)b * 512 + c] = hh;
    pl[(size_t)b * 512 + c] = ll;
  }
  __shared__ float red[4];
  s = bsum64(s);
  if ((tid & 63) == 0) red[tid >> 6] = s;
  __syncthreads();
  if (tid == 0) sq[b] = (red[0] + red[1]) + (red[2] + red[3]);
}

// W1 conversions: straight split (w1_h/l) AND k-padded transpose (w1t_h/l),
// one read of W1 via a 32x32 LDS tile (was two separate kernels).
__global__ __launch_bounds__(256)
void conv_w1(const float* __restrict__ W1,
             unsigned short* __restrict__ th, unsigned short* __restrict__ tl,
             unsigned short* __restrict__ wh, unsigned short* __restrict__ wl) {
  __shared__ float tile[32][33];
  const int tx = threadIdx.x & 31, ty = threadIdx.x >> 5;   // 32 x 8
  const int kb = blockIdx.x * 32, hb = blockIdx.y * 32;
  #pragma unroll
  for (int j = 0; j < 4; j++) {
    int k = kb + ty + j * 8;
    float v = (k < 528) ? W1[(size_t)k * 1024 + hb + tx] : 0.f;
    tile[ty + j * 8][tx] = v;
    if (k < 528) {
      unsigned short hh, ll; split_bf16(v, &hh, &ll);
      wh[(size_t)k * 1024 + hb + tx] = hh;
      wl[(size_t)k * 1024 + hb + tx] = ll;
    }
  }
  __syncthreads();
  #pragma unroll
  for (int j = 0; j < 4; j++) {
    int hrow = hb + ty + j * 8;
    float v = tile[tx][ty + j * 8];
    unsigned short hh, ll; split_bf16(v, &hh, &ll);
    th[(size_t)hrow * 544 + kb + tx] = hh;
    tl[(size_t)hrow * 544 + kb + tx] = ll;
  }
}

// ---- split-bf16 MFMA NT GEMM (64x64 tile; round-8 showed 128-tiles regress:
// staging is L2-resident so bigger tiles only add reg/LDS pressure) ----
// PASSES=3: hi*hi + hi*lo + lo*hi (~fp32). PASSES=1: hi*hi only (~bf16) —
// used for G, whose only consumer is neighbor SELECTION.
// EPI=0: f32 C. EPI=1: zact epilogue -> bf16-split act. EPI=2: bf16-split C.
template <int EPI, int PASSES>
__global__ __launch_bounds__(256)
void mfma_nt(const unsigned short* __restrict__ Ah, const unsigned short* __restrict__ Al, int lda,
             const unsigned short* __restrict__ Bh, const unsigned short* __restrict__ Bl, int ldb,
             int K, float* __restrict__ C, int ldc,
             const float* __restrict__ b1, const float* __restrict__ W2,
             unsigned short* __restrict__ acth, unsigned short* __restrict__ actl) {
  __shared__ unsigned short sAh[64 * 40], sBh[64 * 40];
  __shared__ unsigned short sAl[PASSES == 3 ? 64 * 40 : 16];
  __shared__ unsigned short sBl[PASSES == 3 ? 64 * 40 : 16];
  const int tid = threadIdx.x;
  const int lane = tid & 63, wv = tid >> 6;
  const int wm = wv >> 1, wn = wv & 1;
  const int lr = lane & 15, lq = lane >> 4;
  const int m0 = blockIdx.y * 64, n0 = blockIdx.x * 64;
  const int srow = tid >> 2, sk = (tid & 3) * 8;
  f32x4 acc[2][2];
  #pragma unroll
  for (int mt = 0; mt < 2; mt++)
    #pragma unroll
    for (int nt = 0; nt < 2; nt++)
      #pragma unroll
      for (int i = 0; i < 4; i++) acc[mt][nt][i] = 0.f;

  for (int kb = 0; kb < K; kb += 32) {
    float4 va = *(const float4*)(Ah + (size_t)(m0 + srow) * lda + kb + sk);
    float4 vc = *(const float4*)(Bh + (size_t)(n0 + srow) * ldb + kb + sk);
    float4 vb, vd;
    if (PASSES == 3) {
      vb = *(const float4*)(Al + (size_t)(m0 + srow) * lda + kb + sk);
      vd = *(const float4*)(Bl + (size_t)(n0 + srow) * ldb + kb + sk);
    }
    __syncthreads();
    *(float4*)&sAh[srow * 40 + sk] = va;
    *(float4*)&sBh[srow * 40 + sk] = vc;
    if (PASSES == 3) {
      *(float4*)&sAl[srow * 40 + sk] = vb;
      *(float4*)&sBl[srow * 40 + sk] = vd;
    }
    __syncthreads();
    s16x8 fah[2], fal[2], fbh[2], fbl[2];
    #pragma unroll
    for (int mt = 0; mt < 2; mt++) {
      const int r = wm * 32 + mt * 16 + lr;
      fah[mt] = *(const s16x8*)&sAh[r * 40 + lq * 8];
      if (PASSES == 3) fal[mt] = *(const s16x8*)&sAl[r * 40 + lq * 8];
    }
    #pragma unroll
    for (int nt = 0; nt < 2; nt++) {
      const int r = wn * 32 + nt * 16 + lr;
      fbh[nt] = *(const s16x8*)&sBh[r * 40 + lq * 8];
      if (PASSES == 3) fbl[nt] = *(const s16x8*)&sBl[r * 40 + lq * 8];
    }
    #pragma unroll
    for (int mt = 0; mt < 2; mt++)
      #pragma unroll
      for (int nt = 0; nt < 2; nt++)
        acc[mt][nt] = __builtin_amdgcn_mfma_f32_16x16x32_bf16(fah[mt], fbh[nt], acc[mt][nt], 0, 0, 0);
    if (PASSES == 3) {
      #pragma unroll
      for (int mt = 0; mt < 2; mt++)
        #pragma unroll
        for (int nt = 0; nt < 2; nt++)
          acc[mt][nt] = __builtin_amdgcn_mfma_f32_16x16x32_bf16(fah[mt], fbl[nt], acc[mt][nt], 0, 0, 0);
      #pragma unroll
      for (int mt = 0; mt < 2; mt++)
        #pragma unroll
        for (int nt = 0; nt < 2; nt++)
          acc[mt][nt] = __builtin_amdgcn_mfma_f32_16x16x32_bf16(fal[mt], fbh[nt], acc[mt][nt], 0, 0, 0);
    }
  }

  // C/D layout: row=(lane>>4)*4+reg, col=lane&15  [verified m89/m91]
  #pragma unroll
  for (int nt = 0; nt < 2; nt++) {
    const int n = n0 + wn * 32 + nt * 16 + lr;
    float bb = 0.f, ww = 0.f;
    if (EPI == 1) { bb = b1[n]; ww = W2[n]; }
    #pragma unroll
    for (int mt = 0; mt < 2; mt++) {
      #pragma unroll
      for (int r = 0; r < 4; r++) {
        const int m = m0 + wm * 32 + mt * 16 + lq * 4 + r;
        float v = acc[mt][nt][r];
        if (EPI == 0) {
          C[(size_t)m * ldc + n] = v;
        } else if (EPI == 1) {
          float z = v + bb;
          float e = __builtin_amdgcn_exp2f(fabsf(z) * -2.885390082f);
          float rc = __builtin_amdgcn_rcpf(1.f + e);
          float s = 4.f * e * rc * rc * ww;
          unsigned short hh, ll; split_bf16(s, &hh, &ll);
          acth[(size_t)m * ldc + n] = hh;
          actl[(size_t)m * ldc + n] = ll;
        } else {
          unsigned short hh, ll; split_bf16(v, &hh, &ll);
          acth[(size_t)m * ldc + n] = hh;
          actl[(size_t)m * ldc + n] = ll;
        }
      }
    }
  }
}

// ---- batched S builder (K-slab, 4 blocks/CU) ----
// Sx[0:50][0:50] = neighbor Gram (pre-centering), Sx[50][0:50] = q_k.
__global__ __launch_bounds__(256)
void sbuild_kernel(const unsigned short* __restrict__ ph, const unsigned short* __restrict__ pl,
                   const unsigned short* __restrict__ gh, const unsigned short* __restrict__ gl,
                   const int* __restrict__ idx, float* __restrict__ Sx) {
  __shared__ unsigned short sh[64 * SROW];
  __shared__ unsigned short sl[64 * SROW];
  __shared__ int ids[K_];
  const int b = blockIdx.x;
  const int tid = threadIdx.x;
  if (tid < K_) ids[tid] = idx[b * K_ + tid];
  const int lane = tid & 63, wv = tid >> 6;
  const int wm = wv >> 1, wn = wv & 1;
  const int lr = lane & 15, lq = lane >> 4;
  const int strow = tid >> 4, stk = (tid & 15) * 8;
  __syncthreads();

  f32x4 acc[2][2];
  #pragma unroll
  for (int mt = 0; mt < 2; mt++)
    #pragma unroll
    for (int nt = 0; nt < 2; nt++)
      #pragma unroll
      for (int i = 0; i < 4; i++) acc[mt][nt][i] = 0.f;

  for (int kb = 0; kb < 512; kb += SLAB) {
    __syncthreads();
    #pragma unroll
    for (int p = 0; p < 4; p++) {
      const int r = p * 16 + strow;
      if (r < 51) {
        const unsigned short* srch = (r < 50) ? ph + (size_t)ids[r] * 512 : gh + (size_t)b * 512;
        const unsigned short* srcl = (r < 50) ? pl + (size_t)ids[r] * 512 : gl + (size_t)b * 512;
        *(float4*)&sh[r * SROW + stk] = *(const float4*)(srch + kb + stk);
        *(float4*)&sl[r * SROW + stk] = *(const float4*)(srcl + kb + stk);
      }
    }
    __syncthreads();
    #pragma unroll
    for (int kk = 0; kk < SLAB; kk += 32) {
      s16x8 fah[2], fal[2], fbh[2], fbl[2];
      #pragma unroll
      for (int mt = 0; mt < 2; mt++) {
        const int r = wm * 32 + mt * 16 + lr;
        fah[mt] = *(const s16x8*)&sh[r * SROW + kk + lq * 8];
        fal[mt] = *(const s16x8*)&sl[r * SROW + kk + lq * 8];
      }
      #pragma unroll
      for (int nt = 0; nt < 2; nt++) {
        const int r = wn * 32 + nt * 16 + lr;
        fbh[nt] = *(const s16x8*)&sh[r * SROW + kk + lq * 8];
        fbl[nt] = *(const s16x8*)&sl[r * SROW + kk + lq * 8];
      }
      #pragma unroll
      for (int mt = 0; mt < 2; mt++)
        #pragma unroll
        for (int nt = 0; nt < 2; nt++)
          acc[mt][nt] = __builtin_amdgcn_mfma_f32_16x16x32_bf16(fah[mt], fbh[nt], acc[mt][nt], 0, 0, 0);
      #pragma unroll
      for (int mt = 0; mt < 2; mt++)
        #pragma unroll
        for (int nt = 0; nt < 2; nt++)
          acc[mt][nt] = __builtin_amdgcn_mfma_f32_16x16x32_bf16(fah[mt], fbl[nt], acc[mt][nt], 0, 0, 0);
      #pragma unroll
      for (int mt = 0; mt < 2; mt++)
        #pragma unroll
        for (int nt = 0; nt < 2; nt++)
          acc[mt][nt] = __builtin_amdgcn_mfma_f32_16x16x32_bf16(fal[mt], fbh[nt], acc[mt][nt], 0, 0, 0);
    }
  }

  float* Sb = Sx + (size_t)b * SX_STRIDE;
  #pragma unroll
  for (int nt = 0; nt < 2; nt++) {
    const int n = wn * 32 + nt * 16 + lr;
    #pragma unroll
    for (int mt = 0; mt < 2; mt++) {
      #pragma unroll
      for (int r = 0; r < 4; r++) {
        const int m = wm * 32 + mt * 16 + lq * 4 + r;
        if (m < 51 && n < 52) Sb[m * 52 + n] = acc[mt][nt][r];
      }
    }
  }
}

// monotonic float->uint map (unsigned compare == float compare)
__device__ __forceinline__ unsigned fkey(float f) {
  unsigned u = __float_as_uint(f);
  return u ^ ((unsigned)((int)u >> 31) | 0x80000000u);
}

// Per row b (one wave): the 50-smallest SET via radix bisection on the key,
// not 50 serial extractions. Find V = 51st-smallest key (early exit when
// count(<cand)==50: that set is already the answer); emit {key < V} with
// ballot prefix positions; fill ties at V by index order (never fires for
// random distinct floats, correct if it does). ~150 DS ops vs 600 before.
__global__ __launch_bounds__(64)
void topk_kernel(const float* __restrict__ G, const float* __restrict__ sq,
                 int* __restrict__ idx) {
  const int b = blockIdx.x, lane = threadIdx.x;
  const float* row = G + (size_t)b * 2048;
  unsigned k[32];
  #pragma unroll
  for (int i = 0; i < 32; i++) {
    const int j = i * 64 + lane;
    k[i] = fkey(sq[j] - 2.f * row[j]);
  }
  unsigned V = 0;
  bool exact = false;
  for (int bit = 31; bit >= 0; bit--) {
    const unsigned cand = V | (1u << bit);
    int cnt = 0;
    #pragma unroll
    for (int i = 0; i < 32; i++) cnt += (k[i] < cand) ? 1 : 0;
    #pragma unroll
    for (int o = 1; o < 64; o <<= 1) cnt += __shfl_xor(cnt, o);
    if (cnt == K_) { V = cand; exact = true; break; }   // wave-uniform
    if (cnt < K_ + 1) V = cand;   // 51st-smallest >= cand
  }
  // emit keys < V
  int base = 0;
  #pragma unroll
  for (int i = 0; i < 32; i++) {
    const bool p = (k[i] < V);
    const unsigned long long mask = __ballot(p);
    if (p) {
      const int pos = base + __popcll(mask & ((1ull << lane) - 1ull));
      idx[b * K_ + pos] = i * 64 + lane;
    }
    base += __popcll(mask);
  }
  // ties at V (only when bisection ended without an exact-50 cut)
  if (!exact && base < K_) {
    #pragma unroll
    for (int i = 0; i < 32; i++) {
      if (base >= K_) break;
      const bool p = (k[i] == V);
      const unsigned long long mask = __ballot(p);
      if (p) {
        const int pos = base + __popcll(mask & ((1ull << lane) - 1ull));
        if (pos < K_) idx[b * K_ + pos] = i * 64 + lane;
      }
      base += __popcll(mask);
    }
  }
}

// Per batch (one wave): read precomputed Sx (coalesced), double-center, one-sided
// Jacobi. Column exchange via LDS b128 (13 reads + 13 writes per round; round 12:
// 93 -> 78 us vs bpermute). Single wave => wave-synchronous, no barriers.
__global__ __launch_bounds__(64, 2)
void final_kernel(const float* __restrict__ Sx, float* __restrict__ out) {
  __shared__ float cols[64 * FS];
  const int b = blockIdx.x;
  const int lane = threadIdx.x;
  const float* Sb = Sx + (size_t)b * SX_STRIDE;

  float q = (lane < K_) ? Sb[50 * 52 + lane] : 0.f;
  float qm = bsum64(q) * (1.f / K_);
  float w = (lane < K_) ? (q - qm) : 0.f;

  float f[K_];
  #pragma unroll
  for (int r = 0; r < K_; r++)
    f[r] = (lane < K_) ? Sb[r * 52 + lane] : 0.f;

  float cm = 0.f;
  #pragma unroll
  for (int r = 0; r < K_; r++) cm += f[r];
  cm *= (1.f / K_);
  float gs = bsum64(lane < K_ ? cm : 0.f) * (1.f / K_);
  float cs = cm - gs;
  #pragma unroll
  for (int r = 0; r < K_; r++) {
    float rm = __shfl(cm, r);
    if (lane < K_) f[r] -= rm + cs;
  }

  float nrm = 0.f;
  #pragma unroll
  for (int r = 0; r < K_; r++) nrm += f[r] * f[r];

  float* my = &cols[lane * FS];
  #pragma unroll
  for (int k = 0; k < 12; k++) {
    float4 t = {f[4 * k], f[4 * k + 1], f[4 * k + 2], f[4 * k + 3]};
    *(float4*)&my[4 * k] = t;
  }
  {
    float4 t = {f[48], f[49], nrm, w};
    *(float4*)&my[48] = t;
  }

  for (int sweep = 0; sweep < NSWEEP; sweep++) {
    for (int r = 0; r < 49; r++) {
      const int kk = (25 * r) % 49;
      int m;
      if (lane >= K_)      m = lane;
      else if (lane == 49) m = kk;
      else if (lane == kk) m = 49;
      else { m = (r - lane) % 49; if (m < 0) m += 49; }

      const float* pc = &cols[m * FS];
      float y[52];
      #pragma unroll
      for (int k = 0; k < 13; k++) {
        float4 t = *(const float4*)&pc[4 * k];
        y[4 * k] = t.x; y[4 * k + 1] = t.y; y[4 * k + 2] = t.z; y[4 * k + 3] = t.w;
      }
      float onrm = y[50];
      float yw   = y[51];

      float d0 = 0.f, d1 = 0.f, d2 = 0.f, d3 = 0.f;
      #pragma unroll
      for (int r2 = 0; r2 < 48; r2 += 4) {
        d0 += f[r2] * y[r2];
        d1 += f[r2 + 1] * y[r2 + 1];
        d2 += f[r2 + 2] * y[r2 + 2];
        d3 += f[r2 + 3] * y[r2 + 3];
      }
      d0 += f[48] * y[48];
      d1 += f[49] * y[49];
      float dot = (d0 + d1) + (d2 + d3);

      const bool isp = lane < m;
      float alpha = isp ? nrm : onrm;
      float beta  = isp ? onrm : nrm;
      float tau = (beta - alpha) * 0.5f * __builtin_amdgcn_rcpf(dot);
      float sg = (tau >= 0.f) ? 1.f : -1.f;
      float s1 = __builtin_amdgcn_sqrtf(1.f + tau * tau);
      float tt = sg * __builtin_amdgcn_rcpf(fabsf(tau) + s1);
      float cc = __builtin_amdgcn_rsqf(1.f + tt * tt);
      float ssv = tt * cc;
      float sr = isp ? -ssv : ssv;
      if (lane >= K_ || fabsf(dot) < 1e-20f) { cc = 1.f; sr = 0.f; }
      #pragma unroll
      for (int r2 = 0; r2 < K_; r2++) f[r2] = cc * f[r2] + sr * y[r2];
      w = cc * w + sr * yw;
      nrm = cc * cc * nrm + sr * sr * onrm + 2.f * cc * sr * dot;

      #pragma unroll
      for (int k = 0; k < 12; k++) {
        float4 t = {f[4 * k], f[4 * k + 1], f[4 * k + 2], f[4 * k + 3]};
        *(float4*)&my[4 * k] = t;
      }
      float4 t = {f[48], f[49], nrm, w};
      *(float4*)&my[48] = t;
    }
  }

  float n2 = 0.f;
  #pragma unroll
  for (int r2 = 0; r2 < K_; r2++) n2 += f[r2] * f[r2];
  int rank = 0;
  #pragma unroll
  for (int j = 0; j < K_; j++) {
    float vj = __shfl(n2, j);
    rank += (vj > n2 || (vj == n2 && j < lane)) ? 1 : 0;
  }
  float lam = sqrtf(n2);
  float contrib = (lane < K_ && rank < M_) ? (w * w / lam) : 0.f;
  contrib = bsum64(contrib);
  if (lane == 0) atomicAdd(out, contrib * (1.f / B_));
}

extern "C" void kernel_launch(void* const* d_in, const int* in_sizes, int n_in,
                              void* d_out, int out_size, void* d_ws, size_t ws_size,
                              hipStream_t stream) {
  const float* x  = (const float*)d_in[0];
  const float* t  = (const float*)d_in[1];
  const float* P  = (const float*)d_in[2];
  const float* W1 = (const float*)d_in[3];
  const float* b1 = (const float*)d_in[4];
  const float* W2 = (const float*)d_in[5];
  // d_in[6] = b2: does not affect the gradient; unused.
  float* out = (float*)d_out;

  // workspace layout (~43 MB). Sx aliases G (dead after topk) + xt/w1t (dead
  // after the zact GEMM) — safe because sbuild runs after all of them.
  float* G    = (float*)d_ws;                         // 2048*2048 f32 (16 MB)
  float* Sx   = (float*)d_ws;                         // alias (21.7 MB)
  unsigned short* xt_h  = (unsigned short*)(G + (size_t)B_ * B_);  // [2048][544]
  unsigned short* xt_l  = xt_h  + (size_t)B_ * 544;
  unsigned short* w1t_h = xt_l  + (size_t)B_ * 544;   // [1024][544]
  unsigned short* w1t_l = w1t_h + (size_t)H_ * 544;
  unsigned short* w1_h  = w1t_l + (size_t)H_ * 544;   // [528][1024]
  unsigned short* w1_l  = w1_h  + (size_t)528 * H_;
  unsigned short* p_h   = w1_l  + (size_t)528 * H_;   // [2048][512]
  unsigned short* p_l   = p_h   + (size_t)B_ * D_;
  unsigned short* act_h = p_l   + (size_t)B_ * D_;    // [2048][1024]
  unsigned short* act_l = act_h + (size_t)B_ * H_;
  unsigned short* g_h   = act_l + (size_t)B_ * H_;    // [2048][512]
  unsigned short* g_l   = g_h   + (size_t)B_ * D_;
  float* sq   = (float*)(g_l + (size_t)B_ * D_);      // 2048
  int*   idx  = (int*)(sq + B_);                      // 2048*50

  hipMemsetAsync(d_out, 0, sizeof(float), stream);

  // fused conversions (12 -> 9 launches vs round 12)
  prep_rows<<<B_, 256, 0, stream>>>(x, t, P, xt_h, xt_l, p_h, p_l, sq);
  conv_w1<<<dim3(17, 32), 256, 0, stream>>>(W1, w1t_h, w1t_l, w1_h, w1_l);

  // act = sech^2(xt@W1 + b1) * W2   (3-pass, bf16-split output, fused epilogue)
  mfma_nt<1, 3><<<dim3(H_ / 64, B_ / 64), 256, 0, stream>>>(
      xt_h, xt_l, 544, w1t_h, w1t_l, 544, 544,
      nullptr, H_, b1, W2, act_h, act_l);
  // grad[b,d] = sum_h act[b,h] * W1[d,h]  (3-pass -> bf16-split output)
  mfma_nt<2, 3><<<dim3(D_ / 64, B_ / 64), 256, 0, stream>>>(
      act_h, act_l, H_, w1_h, w1_l, H_, H_,
      nullptr, D_, nullptr, nullptr, g_h, g_l);
  // G = P @ P^T  (1-pass hi-only: selection-grade precision is sufficient)
  mfma_nt<0, 1><<<dim3(B_ / 64, B_ / 64), 256, 0, stream>>>(
      p_h, nullptr, D_, p_h, nullptr, D_, D_,
      G, B_, nullptr, nullptr, nullptr, nullptr);

  topk_kernel<<<B_, 64, 0, stream>>>(G, sq, idx);
  sbuild_kernel<<<B_, 256, 0, stream>>>(p_h, p_l, g_h, g_l, idx, Sx);
  final_kernel<<<B_, 64, 0, stream>>>(Sx, out);
}